// Round 7
// baseline (109.315 us; speedup 1.0000x reference)
//
#include <hip/hip_runtime.h>
#include <math.h>

#define Hdim    256                    // embedding dim
#define NMAX    8192
#define NPADMAX (NMAX + 6 * 32)        // classes 1..6 bucketed, padded to 32
#define WLMAX   264                    // max 32-anchor tiles
#define NSPLIT  2                      // j-range splits per tile
#define SIMGRID 256                    // sim grid (w-loop handles T*NSPLIT > grid)
#define BIGV    1e9f
#define MARGIN  0.5f

typedef __attribute__((ext_vector_type(8))) short bf16x8;   // MFMA A/B frag
typedef __attribute__((ext_vector_type(4))) float f32x4;    // MFMA C/D frag

struct WS {
    unsigned short ebf[NMAX][Hdim];    // normalized bf16 rows at ORIGINAL positions
    int idx[NPADMAX];                  // gathered slot -> original row (pad -> 0)
    int labG[NPADMAX];                 // gathered labels (-1 = pad)
    unsigned hpK[NPADMAX];             // hardest-pos keys (min), order-preserving
    unsigned hnK[NPADMAX];             // hardest-neg keys (max)
    int S[8];                          // S[1..6] bucket starts, S[7] = padded end
    int n[8];                          // real bucket counts
    int wl_a[WLMAX];                   // worklist: anchor base (gathered space)
    int wl_c[WLMAX];                   // worklist: class
    int T;                             // worklist length
    unsigned done;                     // sim completion counter
};

__device__ inline unsigned short f2bf(float f) {    // fp32 -> bf16 RNE
    unsigned u = __float_as_uint(f);
    return (unsigned short)((u + 0x7fffu + ((u >> 16) & 1u)) >> 16);
}
__device__ inline unsigned fkey(float f) {          // order-preserving float->uint
    unsigned u = __float_as_uint(f);
    return (u & 0x80000000u) ? ~u : (u | 0x80000000u);
}
__device__ inline float funkey(unsigned k) {
    unsigned u = (k & 0x80000000u) ? (k & 0x7fffffffu) : ~k;
    return __uint_as_float(u);
}

// ---- K1: block 0 plans (labels only) WHILE blocks 1..512 normalize (embeddings only) ----
// Inverted gather: norm writes at original positions; sim gathers via ws->idx.
__global__ __launch_bounds__(256) void prep_kernel(const float* __restrict__ in,
                                                   const int* __restrict__ lab,
                                                   WS* ws, int N) {
    const int b = blockIdx.x, tid = threadIdx.x;
    if (b == 0) {
        // ---- plan: hist -> bucket layout -> worklist -> idx/labG scatter ----
        __shared__ int h[8], S[8], cur[8];
        if (tid < 8) h[tid] = 0;
        __syncthreads();
        for (int i = tid; i < N; i += 256) {
            int l = lab[i];
            if (l >= 1 && l <= 6) atomicAdd(&h[l], 1);
        }
        __syncthreads();
        if (tid == 0) {
            int acc = 0; S[0] = 0;
            for (int c = 1; c <= 6; ++c) { S[c] = acc; acc += ((h[c] + 31) >> 5) << 5; }
            S[7] = acc;
            int T = 0;
            for (int c = 1; c <= 6; ++c) {
                int nt = (h[c] + 31) >> 5;
                for (int k = 0; k < nt; ++k) { ws->wl_a[T] = S[c] + 32 * k; ws->wl_c[T] = c; ++T; }
            }
            ws->T = T;
            ws->done = 0u;
            for (int c = 0; c < 8; ++c) { ws->n[c] = h[c]; ws->S[c] = S[c]; }
        }
        __syncthreads();
        const int SEnd = S[7];
        for (int g = tid; g < SEnd; g += 256) { ws->idx[g] = 0; ws->labG[g] = -1; }
        if (tid < 8) cur[tid] = S[tid];
        __syncthreads();
        for (int i = tid; i < N; i += 256) {           // scatter (bucket order arbitrary: min/max invariant)
            int l = lab[i];
            if (l >= 1 && l <= 6) { int g = atomicAdd(&cur[l], 1); ws->idx[g] = i; ws->labG[g] = l; }
        }
    } else {
        // ---- normalize 16 rows (4 waves x 4 rows), write bf16 at original position ----
        const int wave = tid >> 6, lane = tid & 63;
        const int r0 = (b - 1) * 16 + wave * 4;
        #pragma unroll
        for (int k = 0; k < 4; ++k) {
            int row = r0 + k;
            if (row < N) {
                float4 v = ((const float4*)(in + (size_t)row * Hdim))[lane];
                float ss = v.x*v.x + v.y*v.y + v.z*v.z + v.w*v.w;
                #pragma unroll
                for (int off = 32; off >= 1; off >>= 1) ss += __shfl_xor(ss, off);
                float sc = 1.0f / fmaxf(sqrtf(ss), 1e-12f);
                ushort4 o;
                o.x = f2bf(v.x * sc); o.y = f2bf(v.y * sc);
                o.z = f2bf(v.z * sc); o.w = f2bf(v.w * sc);
                ((ushort4*)(&ws->ebf[row][0]))[lane] = o;
            }
        }
        // ---- sentinel-init slice of the key arrays (no plan dependency: full NPADMAX) ----
        if (tid < 17) {
            int g = (b - 1) * 17 + tid;                // 512*17 = 8704 >= NPADMAX
            if (g < NPADMAX) { ws->hpK[g] = 0xFFFFFFFFu; ws->hnK[g] = 0u; }
        }
    }
}

// ---- K2: sim tiles (T*NSPLIT work items over 256 blocks) + fused last-block finalize ----
__global__ __launch_bounds__(256) void sim_kernel(WS* ws, float* __restrict__ out) {
    const int wave = threadIdx.x >> 6;
    const int lane = threadIdx.x & 63;
    const int col  = lane & 15;            // C col = j index
    const int quad = lane >> 4;            // C row group
    const int T    = ws->T;

    __shared__ float lds_hp[4][32], lds_hn[4][32];

    for (int w = blockIdx.x; w < T * NSPLIT; w += gridDim.x) {
        const int tileIdx = w >> 1, split = w & 1;
        const int aBase = ws->wl_a[tileIdx];
        const int c     = ws->wl_c[tileIdx];
        const int p     = ((c - 1) ^ 1) + 1;          // confused partner: (1,2)(3,4)(5,6)
        const int posS = ws->S[c], posRealE = posS + ws->n[c];
        const int negS = ws->S[p], negRealE = negS + ws->n[p];
        const int nPosT = (ws->S[c + 1] - posS) >> 4; // padded end of bucket x is S[x+1]
        const int nNegT = (ws->S[p + 1] - negS) >> 4;
        const int nTT   = nPosT + nNegT;

        const unsigned short* ebf = &ws->ebf[0][0];
        const int* __restrict__ idx = ws->idx;

        bf16x8 afrag[2][8];                            // A frags: [m=col][k=quad*8+j], rows via idx
        #pragma unroll
        for (int t2 = 0; t2 < 2; ++t2) {
            int row = idx[aBase + t2 * 16 + col];
            const unsigned short* rp = ebf + (size_t)row * Hdim + quad * 8;
            #pragma unroll
            for (int ks = 0; ks < 8; ++ks)
                afrag[t2][ks] = *(const bf16x8*)(rp + ks * 32);
        }

        float runMin[2][4], runMax[2][4];
        #pragma unroll
        for (int t2 = 0; t2 < 2; ++t2)
            #pragma unroll
            for (int r = 0; r < 4; ++r) { runMin[t2][r] = BIGV; runMax[t2][r] = -BIGV; }

        auto j0Of = [&](int t) -> int {
            return (t < nPosT) ? (posS + (t << 4)) : (negS + ((t - nPosT) << 4));
        };
        bf16x8 b0[8], b1[8];
        auto loadB = [&](bf16x8 (&bf)[8], int t) {
            int row = idx[j0Of(t) + col];
            const unsigned short* rp = ebf + (size_t)row * Hdim + quad * 8;
            #pragma unroll
            for (int ks = 0; ks < 8; ++ks)
                bf[ks] = *(const bf16x8*)(rp + ks * 32);
        };
        auto computeT = [&](bf16x8 (&bf)[8], int t) {
            int j0 = j0Of(t);
            bool isPos = t < nPosT;                    // wave-uniform
            int realE  = isPos ? posRealE : negRealE;
            bool valid = (j0 + col) < realE;           // positional mask, 1 v_cmp/tile
            #pragma unroll
            for (int t2 = 0; t2 < 2; ++t2) {
                f32x4 acc = {0.f, 0.f, 0.f, 0.f};
                #pragma unroll
                for (int ks = 0; ks < 8; ++ks)
                    acc = __builtin_amdgcn_mfma_f32_16x16x32_bf16(afrag[t2][ks], bf[ks], acc, 0, 0, 0);
                if (isPos) {                           // self-sim is max => min unaffected (n>=2 gated)
                    #pragma unroll
                    for (int r = 0; r < 4; ++r)
                        runMin[t2][r] = fminf(runMin[t2][r], valid ? acc[r] : BIGV);
                } else {
                    #pragma unroll
                    for (int r = 0; r < 4; ++r)
                        runMax[t2][r] = fmaxf(runMax[t2][r], valid ? acc[r] : -BIGV);
                }
            }
        };

        // tiles t ≡ split (mod 2), strided by wave: t = split + 2*wave + 8*i; register dbuf
        const int first = split + NSPLIT * wave;
        int nIter = (nTT > first) ? ((nTT - first + 7) >> 3) : 0;
        int t = first, i = 0;
        if (nIter > 0) loadB(b0, t);
        while (i + 2 <= nIter) {
            loadB(b1, t + 8);
            computeT(b0, t);
            if (i + 2 < nIter) loadB(b0, t + 16);
            computeT(b1, t + 8);
            t += 16; i += 2;
        }
        if (i < nIter) computeT(b0, t);

        // reduce across 16 cols; col==0 lanes stash per-wave results in LDS
        #pragma unroll
        for (int t2 = 0; t2 < 2; ++t2)
            #pragma unroll
            for (int r = 0; r < 4; ++r) {
                float mn = runMin[t2][r], mx = runMax[t2][r];
                #pragma unroll
                for (int off = 1; off < 16; off <<= 1) {
                    mn = fminf(mn, __shfl_xor(mn, off));
                    mx = fmaxf(mx, __shfl_xor(mx, off));
                }
                if (col == 0) {
                    int a = t2 * 16 + quad * 4 + r;
                    lds_hp[wave][a] = mn;
                    lds_hn[wave][a] = mx;
                }
            }
        __syncthreads();
        if (wave == 0 && lane < 32) {                  // 64 atomics/block, 2-way contention
            float hp = fminf(fminf(lds_hp[0][lane], lds_hp[1][lane]),
                             fminf(lds_hp[2][lane], lds_hp[3][lane]));
            float hn = fmaxf(fmaxf(lds_hn[0][lane], lds_hn[1][lane]),
                             fmaxf(lds_hn[2][lane], lds_hn[3][lane]));
            int a = aBase + lane;
            if (hp < 1e8f)  atomicMin(&ws->hpK[a], fkey(hp));
            if (hn > -1e8f) atomicMax(&ws->hnK[a], fkey(hn));
        }
        __syncthreads();                               // protect LDS reuse across w-loop
    }

    // ---- completion: drain own atomics, count; last block acquires + finalizes ----
    __shared__ unsigned oldv;
    if (threadIdx.x == 0) {
        __builtin_amdgcn_s_waitcnt(0);                 // data atomics at coherence point
        oldv = atomicAdd(&ws->done, 1u);
    }
    __syncthreads();
    if (oldv != (unsigned)(gridDim.x - 1)) return;
    __threadfence();                                   // one acquire: see all atomic results

    __shared__ int ncls[8];
    if (threadIdx.x < 8) ncls[threadIdx.x] = ws->n[threadIdx.x];
    __syncthreads();
    float sum = 0.f; int cnt = 0;
    const int SEnd = ws->S[7];
    for (int g = threadIdx.x; g < SEnd; g += 256) {
        int l = ws->labG[g];
        if (l >= 1) {                                  // real slot, class 1..6
            int p = ((l - 1) ^ 1) + 1;
            if (ncls[l] >= 2 && ncls[p] >= 1) {        // has_pos && has_neg
                float hp = funkey(ws->hpK[g]);
                float hn = funkey(ws->hnK[g]);
                float tr = MARGIN + hn - hp;
                if (tr > 0.f) sum += tr;
                cnt += 1;
            }
        }
    }
    #pragma unroll
    for (int off = 32; off >= 1; off >>= 1) {
        sum += __shfl_xor(sum, off);
        cnt += __shfl_xor(cnt, off);
    }
    __shared__ float ssum[4]; __shared__ int scnt[4];
    if ((threadIdx.x & 63) == 0) { ssum[threadIdx.x >> 6] = sum; scnt[threadIdx.x >> 6] = cnt; }
    __syncthreads();
    if (threadIdx.x == 0) {
        float ts = ssum[0] + ssum[1] + ssum[2] + ssum[3];
        int   tc = scnt[0] + scnt[1] + scnt[2] + scnt[3];
        out[0] = (tc > 0) ? ts / (float)tc : 0.f;
    }
}

extern "C" void kernel_launch(void* const* d_in, const int* in_sizes, int n_in,
                              void* d_out, int out_size, void* d_ws, size_t ws_size,
                              hipStream_t stream) {
    const float* emb = (const float*)d_in[0];
    const int*   lab = (const int*)d_in[1];
    int N = in_sizes[1];                               // 8192
    WS* ws = (WS*)d_ws;

    prep_kernel<<<1 + (N + 15) / 16, 256, 0, stream>>>(emb, lab, ws, N);
    sim_kernel<<<SIMGRID, 256, 0, stream>>>(ws, (float*)d_out);
}

// Round 8
// 106.308 us; speedup vs baseline: 1.0283x; 1.0283x over previous
//
#include <hip/hip_runtime.h>
#include <math.h>

#define Hdim    256                    // embedding dim
#define NMAX    8192
#define NPADMAX (NMAX + 6 * 32)        // classes 1..6 bucketed, padded to 32
#define WLMAX   264                    // max 32-anchor tiles (worst case 262)
#define NSPLIT  2                      // j-range splits per tile
#define SIMGRID 256
#define BIGV    1e9f
#define MARGIN  0.5f

typedef __attribute__((ext_vector_type(8))) short bf16x8;   // MFMA A/B frag
typedef __attribute__((ext_vector_type(4))) float f32x4;    // MFMA C/D frag

struct WS {
    unsigned short ebf[NPADMAX][Hdim]; // bucket-sorted normalized bf16 rows (classes 1..6)
    int gpos[NMAX];                    // original row -> gathered row (-1 = not bucketed)
    int labG[NPADMAX];                 // gathered labels (-1 = pad)
    unsigned hpK[NPADMAX];             // hardest-pos keys (min), order-preserving
    unsigned hnK[NPADMAX];             // hardest-neg keys (max)
    int S[8];                          // S[1..6] bucket starts, S[7] = padded end
    int n[8];                          // real bucket counts (n[1..6])
    int wl_a[WLMAX];                   // worklist: anchor base (gathered space)
    int wl_c[WLMAX];                   // worklist: class
    int T;                             // worklist length
    unsigned done;                     // sim completion counter
};

__device__ inline unsigned short f2bf(float f) {    // fp32 -> bf16 RNE
    unsigned u = __float_as_uint(f);
    return (unsigned short)((u + 0x7fffu + ((u >> 16) & 1u)) >> 16);
}
__device__ inline unsigned fkey(float f) {          // order-preserving float->uint
    unsigned u = __float_as_uint(f);
    return (u & 0x80000000u) ? ~u : (u | 0x80000000u);
}
__device__ inline float funkey(unsigned k) {
    unsigned u = (k & 0x80000000u) ? (k & 0x7fffffffu) : ~k;
    return __uint_as_float(u);
}

// ---- K1: plan via ballot (no same-address LDS atomic storms) ----
// hist: register counts + wave shuffle-reduce. scatter: ballot + popc-rank,
// ONE LDS atomic per wave x class x iteration (~768 total vs ~12K before).
__global__ __launch_bounds__(1024) void plan_kernel(const int* __restrict__ lab,
                                                    WS* ws, int N) {
    const int tid  = threadIdx.x;
    const int wave = tid >> 6, lane = tid & 63;
    __shared__ int wcnt[16][6];
    __shared__ int S[8];
    __shared__ int cur[6];

    int cnt[6] = {0, 0, 0, 0, 0, 0};
    for (int i = tid; i < N; i += 1024) {            // N multiple of 1024
        int l = lab[i];
        #pragma unroll
        for (int c = 0; c < 6; ++c) cnt[c] += (l == c + 1);
    }
    #pragma unroll
    for (int c = 0; c < 6; ++c) {
        int v = cnt[c];
        #pragma unroll
        for (int off = 32; off >= 1; off >>= 1) v += __shfl_xor(v, off);
        if (lane == 0) wcnt[wave][c] = v;
    }
    __syncthreads();
    if (tid == 0) {
        int h[6];
        #pragma unroll
        for (int c = 0; c < 6; ++c) { int s = 0; for (int w = 0; w < 16; ++w) s += wcnt[w][c]; h[c] = s; }
        int acc = 0; S[0] = 0;
        for (int c = 1; c <= 6; ++c) { S[c] = acc; acc += ((h[c - 1] + 31) >> 5) << 5; }
        S[7] = acc;
        int T = 0;
        for (int c = 1; c <= 6; ++c) {
            int nt = (h[c - 1] + 31) >> 5;
            for (int k = 0; k < nt; ++k) { ws->wl_a[T] = S[c] + 32 * k; ws->wl_c[T] = c; ++T; }
        }
        ws->T = T;
        ws->done = 0u;
        ws->n[0] = 0; ws->n[7] = 0;
        for (int c = 1; c <= 6; ++c) ws->n[c] = h[c - 1];
        for (int c = 0; c < 8; ++c) ws->S[c] = S[c];
    }
    __syncthreads();
    if (tid < 6) cur[tid] = S[tid + 1];              // cur[c-1] = start of class c
    const int SEnd = S[7];
    for (int g = tid; g < SEnd; g += 1024) {         // sentinel init, padded range only
        ws->hpK[g] = 0xFFFFFFFFu; ws->hnK[g] = 0u; ws->labG[g] = -1;
    }
    __syncthreads();
    for (int i = tid; i < N; i += 1024) {            // ballot scatter (order-invariant)
        int l = lab[i];
        int g = -1;
        #pragma unroll
        for (int c = 1; c <= 6; ++c) {
            unsigned long long mask = __ballot(l == c);
            if (mask) {                              // wave-uniform
                int leader = __builtin_ctzll(mask);
                int base = 0;
                if (lane == leader) base = atomicAdd(&cur[c - 1], __popcll(mask));
                base = __shfl(base, leader);
                if (l == c) g = base + __popcll(mask & ((1ULL << lane) - 1ULL));
            }
        }
        if (g >= 0) ws->labG[g] = l;
        ws->gpos[i] = g;
    }
}

// ---- K2: L2-normalize bucketed rows -> bf16 at gathered (contiguous) position ----
__global__ __launch_bounds__(256) void norm_gather_kernel(const float* __restrict__ in,
                                                          WS* ws) {
    int row  = blockIdx.x * 4 + (threadIdx.x >> 6);
    int lane = threadIdx.x & 63;
    int g = ws->gpos[row];                 // wave-uniform
    if (g < 0) return;                     // class not in any confused pair: never read
    float4 v = ((const float4*)(in + (size_t)row * Hdim))[lane];
    float ss = v.x*v.x + v.y*v.y + v.z*v.z + v.w*v.w;
    #pragma unroll
    for (int off = 32; off >= 1; off >>= 1) ss += __shfl_xor(ss, off);
    float sc = 1.0f / fmaxf(sqrtf(ss), 1e-12f);
    ushort4 o;
    o.x = f2bf(v.x * sc); o.y = f2bf(v.y * sc);
    o.z = f2bf(v.z * sc); o.w = f2bf(v.w * sc);
    ((ushort4*)(&ws->ebf[g][0]))[lane] = o;
}

// ---- K3: sim tiles (T*2 work items, contiguous rows) + fused last-block finalize ----
__global__ __launch_bounds__(256) void sim_kernel(WS* ws, float* __restrict__ out) {
    const int wave = threadIdx.x >> 6;
    const int lane = threadIdx.x & 63;
    const int col  = lane & 15;            // C col = j index
    const int quad = lane >> 4;            // C row group
    const int T    = ws->T;

    __shared__ float lds_hp[4][32], lds_hn[4][32];

    for (int w = blockIdx.x; w < T * NSPLIT; w += gridDim.x) {
        const int tileIdx = w >> 1, split = w & 1;
        const int aBase = ws->wl_a[tileIdx];
        const int c     = ws->wl_c[tileIdx];
        const int p     = ((c - 1) ^ 1) + 1;          // confused partner: (1,2)(3,4)(5,6)
        const int posS = ws->S[c], posRealE = posS + ws->n[c];
        const int negS = ws->S[p], negRealE = negS + ws->n[p];
        const int nPosT = (ws->S[c + 1] - posS) >> 4; // padded end of bucket x is S[x+1]
        const int nNegT = (ws->S[p + 1] - negS) >> 4;
        const int nTT   = nPosT + nNegT;

        const unsigned short* ebf = &ws->ebf[0][0];

        bf16x8 afrag[2][8];                            // A frags: [m=col][k=quad*8+j]
        #pragma unroll
        for (int t2 = 0; t2 < 2; ++t2) {
            const unsigned short* rp = ebf + (size_t)(aBase + t2 * 16 + col) * Hdim + quad * 8;
            #pragma unroll
            for (int ks = 0; ks < 8; ++ks)
                afrag[t2][ks] = *(const bf16x8*)(rp + ks * 32);
        }

        float runMin[2][4], runMax[2][4];
        #pragma unroll
        for (int t2 = 0; t2 < 2; ++t2)
            #pragma unroll
            for (int r = 0; r < 4; ++r) { runMin[t2][r] = BIGV; runMax[t2][r] = -BIGV; }

        auto j0Of = [&](int t) -> int {
            return (t < nPosT) ? (posS + (t << 4)) : (negS + ((t - nPosT) << 4));
        };
        bf16x8 b0[8], b1[8];
        auto loadB = [&](bf16x8 (&bf)[8], int t) {
            const unsigned short* rp = ebf + (size_t)(j0Of(t) + col) * Hdim + quad * 8;
            #pragma unroll
            for (int ks = 0; ks < 8; ++ks)
                bf[ks] = *(const bf16x8*)(rp + ks * 32);
        };
        auto computeT = [&](bf16x8 (&bf)[8], int t) {
            int j0 = j0Of(t);
            bool isPos = t < nPosT;                    // wave-uniform
            int realE  = isPos ? posRealE : negRealE;
            bool valid = (j0 + col) < realE;           // positional mask, 1 v_cmp/tile
            #pragma unroll
            for (int t2 = 0; t2 < 2; ++t2) {
                f32x4 acc = {0.f, 0.f, 0.f, 0.f};
                #pragma unroll
                for (int ks = 0; ks < 8; ++ks)
                    acc = __builtin_amdgcn_mfma_f32_16x16x32_bf16(afrag[t2][ks], bf[ks], acc, 0, 0, 0);
                if (isPos) {                           // self-sim is max => min unaffected (n>=2 gated)
                    #pragma unroll
                    for (int r = 0; r < 4; ++r)
                        runMin[t2][r] = fminf(runMin[t2][r], valid ? acc[r] : BIGV);
                } else {
                    #pragma unroll
                    for (int r = 0; r < 4; ++r)
                        runMax[t2][r] = fmaxf(runMax[t2][r], valid ? acc[r] : -BIGV);
                }
            }
        };

        // tiles t ≡ split (mod 2), strided across waves: t = split + 2*(wave + 4*i)
        const int first = split + NSPLIT * wave;
        int nIter = (nTT > first) ? ((nTT - first + 7) >> 3) : 0;
        int t = first, i = 0;
        if (nIter > 0) loadB(b0, t);
        while (i + 2 <= nIter) {                       // register double-buffered
            loadB(b1, t + 8);
            computeT(b0, t);
            if (i + 2 < nIter) loadB(b0, t + 16);
            computeT(b1, t + 8);
            t += 16; i += 2;
        }
        if (i < nIter) computeT(b0, t);

        // reduce across 16 cols; col==0 lanes stash per-wave results in LDS
        #pragma unroll
        for (int t2 = 0; t2 < 2; ++t2)
            #pragma unroll
            for (int r = 0; r < 4; ++r) {
                float mn = runMin[t2][r], mx = runMax[t2][r];
                #pragma unroll
                for (int off = 1; off < 16; off <<= 1) {
                    mn = fminf(mn, __shfl_xor(mn, off));
                    mx = fmaxf(mx, __shfl_xor(mx, off));
                }
                if (col == 0) {
                    int a = t2 * 16 + quad * 4 + r;
                    lds_hp[wave][a] = mn;
                    lds_hn[wave][a] = mx;
                }
            }
        __syncthreads();
        if (wave == 0 && lane < 32) {                  // 64 atomics/block, 2-way contention
            float hp = fminf(fminf(lds_hp[0][lane], lds_hp[1][lane]),
                             fminf(lds_hp[2][lane], lds_hp[3][lane]));
            float hn = fmaxf(fmaxf(lds_hn[0][lane], lds_hn[1][lane]),
                             fmaxf(lds_hn[2][lane], lds_hn[3][lane]));
            int a = aBase + lane;
            if (hp < 1e8f)  atomicMin(&ws->hpK[a], fkey(hp));
            if (hn > -1e8f) atomicMax(&ws->hnK[a], fkey(hn));
        }
        __syncthreads();                               // protect LDS reuse across w-loop
    }

    // ---- completion: drain own atomics (s_waitcnt), count; last block acquires + finalizes ----
    __shared__ unsigned oldv;
    if (threadIdx.x == 0) {
        __builtin_amdgcn_s_waitcnt(0);                 // data atomics at coherence point
        oldv = atomicAdd(&ws->done, 1u);
    }
    __syncthreads();
    if (oldv != (unsigned)(gridDim.x - 1)) return;
    __threadfence();                                   // one acquire: see all atomic results

    __shared__ int ncls[8];
    if (threadIdx.x < 8) ncls[threadIdx.x] = ws->n[threadIdx.x];
    __syncthreads();
    float sum = 0.f; int cnt = 0;
    const int SEnd = ws->S[7];
    for (int g = threadIdx.x; g < SEnd; g += 256) {
        int l = ws->labG[g];
        if (l >= 1) {                                  // real slot, class 1..6
            int p = ((l - 1) ^ 1) + 1;
            if (ncls[l] >= 2 && ncls[p] >= 1) {        // has_pos && has_neg
                float hp = funkey(ws->hpK[g]);
                float hn = funkey(ws->hnK[g]);
                float tr = MARGIN + hn - hp;
                if (tr > 0.f) sum += tr;
                cnt += 1;
            }
        }
    }
    #pragma unroll
    for (int off = 32; off >= 1; off >>= 1) {
        sum += __shfl_xor(sum, off);
        cnt += __shfl_xor(cnt, off);
    }
    __shared__ float ssum[4]; __shared__ int scnt[4];
    if ((threadIdx.x & 63) == 0) { ssum[threadIdx.x >> 6] = sum; scnt[threadIdx.x >> 6] = cnt; }
    __syncthreads();
    if (threadIdx.x == 0) {
        float ts = ssum[0] + ssum[1] + ssum[2] + ssum[3];
        int   tc = scnt[0] + scnt[1] + scnt[2] + scnt[3];
        out[0] = (tc > 0) ? ts / (float)tc : 0.f;
    }
}

extern "C" void kernel_launch(void* const* d_in, const int* in_sizes, int n_in,
                              void* d_out, int out_size, void* d_ws, size_t ws_size,
                              hipStream_t stream) {
    const float* emb = (const float*)d_in[0];
    const int*   lab = (const int*)d_in[1];
    int N = in_sizes[1];                               // 8192
    WS* ws = (WS*)d_ws;

    plan_kernel<<<1, 1024, 0, stream>>>(lab, ws, N);
    norm_gather_kernel<<<(N + 3) / 4, 256, 0, stream>>>(emb, ws);
    sim_kernel<<<SIMGRID, 256, 0, stream>>>(ws, (float*)d_out);
}